// Round 4
// baseline (561.132 us; speedup 1.0000x reference)
//
#include <hip/hip_runtime.h>

typedef unsigned short u16;
typedef unsigned int u32;

#define SEQ 96
#define DM 512
#define NBATCH 512
#define NFREQ 49
#define CUT 16
#define MROWS (NBATCH * SEQ)  // 49152
#define MBLK 64

typedef __attribute__((ext_vector_type(8))) short bf16x8;
typedef __attribute__((ext_vector_type(4))) float f32x4;

// ---------- bf16 helpers (manual, RNE) ----------
__device__ __forceinline__ u16 f2bf(float f) {
  u32 u = __float_as_uint(f);
  u32 r = (u + 0x7fffu + ((u >> 16) & 1u)) >> 16;
  return (u16)r;
}
__device__ __forceinline__ float bf2f(u16 u) {
  return __uint_as_float(((u32)u) << 16);
}

// async global->LDS, 16B per lane. lds ptr must be wave-uniform base.
__device__ __forceinline__ void g2l16(const void* g, void* l) {
  __builtin_amdgcn_global_load_lds(
      (const __attribute__((address_space(1))) void*)g,
      (__attribute__((address_space(3))) void*)l, 16, 0, 0);
}

// ---------- K1: build spectral filter matrices Fl/Fh [96x96] bf16 ----------
__global__ void build_filters_k(const float* __restrict__ w,
                                u16* __restrict__ FlB, u16* __restrict__ FhB) {
  int idx = blockIdx.x * 256 + threadIdx.x;
  if (idx >= SEQ * SEQ) return;
  int s = idx / SEQ, t = idx % SEQ;
  int d = s - t;
  const float scale = 1.0f / (float)SEQ;
  const float w0 = 6.283185307179586f / (float)SEQ;
  float cl = 0.f, ch = 0.f;
  for (int k = 0; k < NFREQ; k++) {
    int m = (k * d) % SEQ;
    if (m < 0) m += SEQ;
    float c = (k == 0 || k == SEQ / 2) ? 1.0f : 2.0f;
    float v = c * w[k] * cosf(w0 * (float)m) * scale;
    if (k < CUT) cl += v; else ch += v;
  }
  FlB[idx] = f2bf(cl);
  FhB[idx] = f2bf(ch);
}

// ---------- K1b: transpose fp32 [K,N] weight -> bf16 [N,K] ----------
__global__ void __launch_bounds__(256) transpose_w_k(
    const float* __restrict__ W, u16* __restrict__ Wt, int K, int N) {
  __shared__ float t[32][33];
  int k0 = blockIdx.x * 32, n0 = blockIdx.y * 32;
  int tx = threadIdx.x & 31, ty = threadIdx.x >> 5;  // ty 0..7
  #pragma unroll
  for (int r = 0; r < 32; r += 8)
    t[ty + r][tx] = W[(size_t)(k0 + ty + r) * N + n0 + tx];
  __syncthreads();
  #pragma unroll
  for (int r = 0; r < 32; r += 8)
    Wt[(size_t)(n0 + ty + r) * K + k0 + tx] = f2bf(t[tx][ty + r]);
}

// ---------- K2a: xT[b][d][t] = bf16(x[b][t][d]) ----------
__global__ void __launch_bounds__(256) xt_k(
    const float* __restrict__ x, u16* __restrict__ xT) {
  __shared__ float xs[SEQ * 65];
  int b = blockIdx.x;
  int d0 = blockIdx.y * 64;
  const float* xb = x + (size_t)b * SEQ * DM + d0;
  #pragma unroll
  for (int v = 0; v < 6; v++) {
    int c = v * 256 + threadIdx.x;   // 0..1535
    int t = c >> 4, dq = (c & 15) << 2;
    float4 f = *(const float4*)(xb + (size_t)t * DM + dq);
    xs[t * 65 + dq + 0] = f.x;
    xs[t * 65 + dq + 1] = f.y;
    xs[t * 65 + dq + 2] = f.z;
    xs[t * 65 + dq + 3] = f.w;
  }
  __syncthreads();
  u32* outw = (u32*)(xT + ((size_t)b * DM + d0) * SEQ);
  #pragma unroll
  for (int v = 0; v < 12; v++) {
    int c = v * 256 + threadIdx.x;   // 0..3071
    int d = c / 48, tw = c % 48;
    int t0 = tw * 2;
    u32 lo = (u32)f2bf(xs[t0 * 65 + d]);
    u32 hi = (u32)f2bf(xs[(t0 + 1) * 65 + d]);
    outw[(size_t)d * 48 + tw] = lo | (hi << 16);
  }
}

// ---------- K2b: xl[b] = Fl @ x[b], xh[b] = Fh @ x[b] via MFMA ----------
__global__ void __launch_bounds__(256) filter_mfma_k(
    const u16* __restrict__ xT, const u16* __restrict__ FlB,
    const u16* __restrict__ FhB, u16* __restrict__ xl, u16* __restrict__ xh) {
  __shared__ __align__(16) u16 lds[128 * SEQ + 2 * SEQ * SEQ];  // 61056 B
  u16* Bs = lds;                 // [128 d][96 t]
  u16* As0 = lds + 128 * SEQ;    // [2][96 s][96 t]
  int tid = threadIdx.x;
  int lane = tid & 63, w = tid >> 6;
  int b = blockIdx.x, d0 = blockIdx.y * 128;

  const u16* xbase = xT + ((size_t)b * DM + d0) * SEQ;
  #pragma unroll
  for (int it = 0; it < 6; it++) {
    int c = it * 256 + tid;
    int row = c / 12, off = (c % 12) * 8;
    g2l16(xbase + (size_t)row * SEQ + off, (char*)Bs + (((it * 256 + w * 64)) << 4));
  }
  #pragma unroll
  for (int it = 0; it < 9; it++) {
    int c = it * 256 + tid;      // 0..2303
    const u16* src = (c < 1152) ? (FlB + c * 8) : (FhB + (c - 1152) * 8);
    g2l16(src, (char*)As0 + ((it * 256 + w * 64) << 4));
  }
  __syncthreads();

  const int l15 = lane & 15, lq = lane >> 4;
  f32x4 acc[2][6][2] = {};
  #pragma unroll
  for (int ks = 0; ks < 3; ks++) {
    int kt = ks * 32;
    bf16x8 bfr[2];
    #pragma unroll
    for (int j = 0; j < 2; j++)
      bfr[j] = *(const bf16x8*)&Bs[(w * 32 + j * 16 + l15) * SEQ + kt + lq * 8];
    #pragma unroll
    for (int f = 0; f < 2; f++)
      #pragma unroll
      for (int i = 0; i < 6; i++) {
        bf16x8 afr = *(const bf16x8*)&As0[f * SEQ * SEQ + (i * 16 + l15) * SEQ + kt + lq * 8];
        #pragma unroll
        for (int j = 0; j < 2; j++)
          acc[f][i][j] = __builtin_amdgcn_mfma_f32_16x16x32_bf16(afr, bfr[j], acc[f][i][j], 0, 0, 0);
      }
  }
  #pragma unroll
  for (int f = 0; f < 2; f++) {
    u16* dst = f ? xh : xl;
    #pragma unroll
    for (int i = 0; i < 6; i++)
      #pragma unroll
      for (int j = 0; j < 2; j++) {
        int d = d0 + w * 32 + j * 16 + l15;
        #pragma unroll
        for (int r = 0; r < 4; r++) {
          int s = i * 16 + lq * 4 + r;
          dst[((size_t)b * SEQ + s) * DM + d] = f2bf(acc[f][i][j][r]);
        }
      }
  }
}

// ---------- K3: proj GEMM, double-buffered LDS, 1 barrier/K-step ----------
// C[M,512] = A[M,512]bf16 @ Wt[512,512]^T + bias. 128x128 tile, 4 waves.
__global__ void __launch_bounds__(256) gemm_proj_mfma_k(
    const u16* __restrict__ xl, const u16* __restrict__ xh,
    const u16* __restrict__ Wlt, const u16* __restrict__ Wht,
    const float* __restrict__ bl, const float* __restrict__ bh,
    u16* __restrict__ yl, u16* __restrict__ yh) {
  const u16* A = blockIdx.z ? xh : xl;
  const u16* Bt = blockIdx.z ? Wht : Wlt;
  const float* bias = blockIdx.z ? bh : bl;
  u16* C = blockIdx.z ? yh : yl;

  // per buffer: A[128][32] (8KB) then B[128][32] (8KB)
  __shared__ __align__(16) char stg[2][16384];
  const int m0 = blockIdx.x * 128;
  const int n0 = blockIdx.y * 128;
  const int tid = threadIdx.x;
  const int lane = tid & 63;
  const int w = tid >> 6;
  const int wm = w & 1, wn = w >> 1;  // 2x2 waves, each 64x64
  const int l15 = lane & 15;
  const int lq = lane >> 4;  // 0..3

  f32x4 acc[4][4] = {};

  // stage K-step ks into buffer b (1024 chunks of 16B: 512 A + 512 B)
  auto stage = [&](int b, int ks) {
    const int kt = ks * 32;
    #pragma unroll
    for (int it = 0; it < 4; it++) {
      int c = it * 256 + tid;
      int row = (c & 511) >> 2, ce = (c & 3) << 3;
      const u16* src = (c < 512)
          ? A  + (size_t)(m0 + row) * 512 + kt + ce
          : Bt + (size_t)(n0 + row) * 512 + kt + ce;
      g2l16(src, stg[b] + ((it * 256 + w * 64) << 4));
    }
  };

  stage(0, 0);
  __syncthreads();

  #pragma unroll 2
  for (int ks = 0; ks < 16; ks++) {
    const int cur = ks & 1;
    if (ks < 15) stage(cur ^ 1, ks + 1);   // loads fly while we compute
    const u16* As = (const u16*)stg[cur];
    const u16* Bs = As + 4096;  // 8KB offset
    bf16x8 af[4], bf[4];
    #pragma unroll
    for (int i = 0; i < 4; i++)
      af[i] = *(const bf16x8*)&As[(wm * 64 + i * 16 + l15) * 32 + lq * 8];
    #pragma unroll
    for (int j = 0; j < 4; j++)
      bf[j] = *(const bf16x8*)&Bs[(wn * 64 + j * 16 + l15) * 32 + lq * 8];
    #pragma unroll
    for (int i = 0; i < 4; i++)
      #pragma unroll
      for (int j = 0; j < 4; j++)
        acc[i][j] = __builtin_amdgcn_mfma_f32_16x16x32_bf16(af[i], bf[j], acc[i][j], 0, 0, 0);
    __syncthreads();  // drains vmcnt (next buf ready) + read-done on cur
  }

  #pragma unroll
  for (int j = 0; j < 4; j++) {
    int n = n0 + wn * 64 + j * 16 + l15;
    float bv = bias[n];
    #pragma unroll
    for (int i = 0; i < 4; i++) {
      int mrow = m0 + wm * 64 + i * 16 + lq * 4;
      #pragma unroll
      for (int r = 0; r < 4; r++)
        C[(size_t)(mrow + r) * 512 + n] = f2bf(acc[i][j][r] + bv);
    }
  }
}

// ---------- K4: gate GEMM (K=1024) + fused y = x + g*yl + (1-g)*yh ----------
// Proven 128x128 / 4-wave / 16KB-LDS shape with 1-barrier double buffer.
// g stays fp32 in registers; y written fp32 (LN numerics preserved).
__global__ void __launch_bounds__(256) gate_y_k(
    const u16* __restrict__ yl, const u16* __restrict__ yh,
    const u16* __restrict__ Wgt, const float* __restrict__ bg,
    const float* __restrict__ x, float* __restrict__ y) {
  __shared__ __align__(16) char stg[2][16384];
  const int m0 = blockIdx.x * 128;
  const int n0 = blockIdx.y * 128;
  const int tid = threadIdx.x;
  const int lane = tid & 63;
  const int w = tid >> 6;
  const int wm = w & 1, wn = w >> 1;  // 2x2 waves, each 64x64
  const int l15 = lane & 15;
  const int lq = lane >> 4;

  // stage K-step ks into buffer b (1024 chunks: 512 A + 512 B)
  auto stage = [&](int b, int ks) {
    const int kt = ks * 32;
    const int ka = kt & 511;
    const u16* Ak = (ks < 16) ? yl : yh;   // concat A along K
    #pragma unroll
    for (int it = 0; it < 4; it++) {
      int c = it * 256 + tid;
      int row = (c & 511) >> 2, ce = (c & 3) << 3;
      const u16* src = (c < 512)
          ? Ak  + (size_t)(m0 + row) * 512 + ka + ce
          : Wgt + (size_t)(n0 + row) * 1024 + kt + ce;
      g2l16(src, stg[b] + ((it * 256 + w * 64) << 4));
    }
  };

  f32x4 acc[4][4] = {};

  stage(0, 0);
  __syncthreads();

  #pragma unroll 2
  for (int ks = 0; ks < 32; ks++) {
    const int cur = ks & 1;
    if (ks < 31) stage(cur ^ 1, ks + 1);
    const u16* As = (const u16*)stg[cur];
    const u16* Bs = As + 4096;  // 8KB offset
    bf16x8 af[4], bf[4];
    #pragma unroll
    for (int i = 0; i < 4; i++)
      af[i] = *(const bf16x8*)&As[(wm * 64 + i * 16 + l15) * 32 + lq * 8];
    #pragma unroll
    for (int j = 0; j < 4; j++)
      bf[j] = *(const bf16x8*)&Bs[(wn * 64 + j * 16 + l15) * 32 + lq * 8];
    #pragma unroll
    for (int i = 0; i < 4; i++)
      #pragma unroll
      for (int j = 0; j < 4; j++)
        acc[i][j] = __builtin_amdgcn_mfma_f32_16x16x32_bf16(af[i], bf[j], acc[i][j], 0, 0, 0);
    __syncthreads();
  }

  // epilogue: g = sigmoid(z + bg) in fp32; y = x + g*yl + (1-g)*yh
  // yl/yh tile re-reads are L2-hot (this block just streamed these rows).
  #pragma unroll
  for (int j = 0; j < 4; j++) {
    const int n = n0 + wn * 64 + j * 16 + l15;
    const float bgv = bg[n];
    #pragma unroll
    for (int i = 0; i < 4; i++) {
      const int mrow = m0 + wm * 64 + i * 16 + lq * 4;
      #pragma unroll
      for (int r = 0; r < 4; r++) {
        const size_t idx = (size_t)(mrow + r) * 512 + n;
        const float z = acc[i][j][r] + bgv;
        const float gv = 1.f / (1.f + __expf(-z));
        const float lv = bf2f(yl[idx]);
        const float hv = bf2f(yh[idx]);
        y[idx] = x[idx] + gv * lv + (1.f - gv) * hv;
      }
    }
  }
}

// ---------- K5: LayerNorm only: out = (y - mu)/sd * gamma + beta ----------
__global__ void __launch_bounds__(256) ln_k(
    const float* __restrict__ y, const float* __restrict__ gamma,
    const float* __restrict__ beta, float* __restrict__ out) {
  __shared__ float red[8];
  const int r = blockIdx.x;
  const size_t base = (size_t)r * 512;
  const int e = threadIdx.x * 2;
  float2 v = *(const float2*)(y + base + e);
  float sum = v.x + v.y;
  float sumsq = v.x * v.x + v.y * v.y;
  #pragma unroll
  for (int off = 32; off; off >>= 1) {
    sum += __shfl_down(sum, off);
    sumsq += __shfl_down(sumsq, off);
  }
  const int wid = threadIdx.x >> 6;
  if ((threadIdx.x & 63) == 0) {
    red[wid] = sum;
    red[4 + wid] = sumsq;
  }
  __syncthreads();
  sum = red[0] + red[1] + red[2] + red[3];
  sumsq = red[4] + red[5] + red[6] + red[7];
  const float mu = sum * (1.f / 512.f);
  const float var = sumsq * (1.f / 512.f) - mu * mu;
  const float inv = rsqrtf(var + 1e-5f);
  float2 gm = *(const float2*)(gamma + e);
  float2 bt = *(const float2*)(beta + e);
  float2 o;
  o.x = (v.x - mu) * inv * gm.x + bt.x;
  o.y = (v.y - mu) * inv * gm.y + bt.y;
  *(float2*)(out + base + e) = o;
}

extern "C" void kernel_launch(void* const* d_in, const int* in_sizes, int n_in,
                              void* d_out, int out_size, void* d_ws, size_t ws_size,
                              hipStream_t stream) {
  const float* x     = (const float*)d_in[0];
  const float* fw    = (const float*)d_in[1];
  const float* Wl    = (const float*)d_in[2];
  const float* bl    = (const float*)d_in[3];
  const float* Wh    = (const float*)d_in[4];
  const float* bh    = (const float*)d_in[5];
  const float* Wg    = (const float*)d_in[6];
  const float* bg    = (const float*)d_in[7];
  const float* gamma = (const float*)d_in[8];
  const float* beta  = (const float*)d_in[9];
  float* out = (float*)d_out;

  char* ws = (char*)d_ws;
  u16* FlB = (u16*)ws;                      // 96*96 bf16
  u16* FhB = FlB + SEQ * SEQ;
  u16* Wlt = (u16*)(ws + 64 * 1024);        // 512x512 bf16 [N][K]
  u16* Wht = Wlt + 512 * 512;
  u16* Wgt = Wht + 512 * 512;               // 512x1024 [N][K]
  size_t tsz = (size_t)MROWS * 512;         // 25165824 elems
  u16* xl = (u16*)(ws + 4 * 1024 * 1024);
  u16* xh = xl + tsz;
  u16* yl = xh + tsz;
  u16* yh = yl + tsz;
  u16* xT = yl;          // [512][512][96] u16 = 48 MB, dead before proj writes yl
  float* yf = (float*)xl;  // y fp32 (96 MB) over xl+xh, dead after proj

  build_filters_k<<<dim3(36), dim3(256), 0, stream>>>(fw, FlB, FhB);
  transpose_w_k<<<dim3(16, 16), dim3(256), 0, stream>>>(Wl, Wlt, 512, 512);
  transpose_w_k<<<dim3(16, 16), dim3(256), 0, stream>>>(Wh, Wht, 512, 512);
  transpose_w_k<<<dim3(32, 16), dim3(256), 0, stream>>>(Wg, Wgt, 1024, 512);
  xt_k<<<dim3(NBATCH, DM / 64), dim3(256), 0, stream>>>(x, xT);
  filter_mfma_k<<<dim3(NBATCH, DM / 128), dim3(256), 0, stream>>>(xT, FlB, FhB, xl, xh);
  gemm_proj_mfma_k<<<dim3(MROWS / 128, 4, 2), dim3(256), 0, stream>>>(
      xl, xh, Wlt, Wht, bl, bh, yl, yh);
  gate_y_k<<<dim3(MROWS / 128, 4), dim3(256), 0, stream>>>(
      yl, yh, Wgt, bg, x, yf);
  ln_k<<<dim3(MROWS), dim3(256), 0, stream>>>(yf, gamma, beta, out);
}

// Round 5
// 439.573 us; speedup vs baseline: 1.2765x; 1.2765x over previous
//
#include <hip/hip_runtime.h>

typedef unsigned short u16;
typedef unsigned int u32;

#define SEQ 96
#define DM 512
#define NBATCH 512
#define NFREQ 49
#define CUT 16
#define MROWS (NBATCH * SEQ)  // 49152

typedef __attribute__((ext_vector_type(8))) short bf16x8;
typedef __attribute__((ext_vector_type(4))) float f32x4;

// ---------- bf16 helpers (manual, RNE) ----------
__device__ __forceinline__ u16 f2bf(float f) {
  u32 u = __float_as_uint(f);
  u32 r = (u + 0x7fffu + ((u >> 16) & 1u)) >> 16;
  return (u16)r;
}
__device__ __forceinline__ float bf2f(u16 u) {
  return __uint_as_float(((u32)u) << 16);
}

// async global->LDS, 16B per lane. lds ptr must be wave-uniform base.
__device__ __forceinline__ void g2l16(const void* g, void* l) {
  __builtin_amdgcn_global_load_lds(
      (const __attribute__((address_space(1))) void*)g,
      (__attribute__((address_space(3))) void*)l, 16, 0, 0);
}

// ---------- K1: build spectral filter matrices Fl/Fh [96x96] bf16 ----------
__global__ void build_filters_k(const float* __restrict__ w,
                                u16* __restrict__ FlB, u16* __restrict__ FhB) {
  int idx = blockIdx.x * 256 + threadIdx.x;
  if (idx >= SEQ * SEQ) return;
  int s = idx / SEQ, t = idx % SEQ;
  int d = s - t;
  const float scale = 1.0f / (float)SEQ;
  const float w0 = 6.283185307179586f / (float)SEQ;
  float cl = 0.f, ch = 0.f;
  for (int k = 0; k < NFREQ; k++) {
    int m = (k * d) % SEQ;
    if (m < 0) m += SEQ;
    float c = (k == 0 || k == SEQ / 2) ? 1.0f : 2.0f;
    float v = c * w[k] * cosf(w0 * (float)m) * scale;
    if (k < CUT) cl += v; else ch += v;
  }
  FlB[idx] = f2bf(cl);
  FhB[idx] = f2bf(ch);
}

// ---------- K1b: transpose fp32 [K,N] weight -> bf16 [N,K] ----------
__global__ void __launch_bounds__(256) transpose_w_k(
    const float* __restrict__ W, u16* __restrict__ Wt, int K, int N) {
  __shared__ float t[32][33];
  int k0 = blockIdx.x * 32, n0 = blockIdx.y * 32;
  int tx = threadIdx.x & 31, ty = threadIdx.x >> 5;  // ty 0..7
  #pragma unroll
  for (int r = 0; r < 32; r += 8)
    t[ty + r][tx] = W[(size_t)(k0 + ty + r) * N + n0 + tx];
  __syncthreads();
  #pragma unroll
  for (int r = 0; r < 32; r += 8)
    Wt[(size_t)(n0 + ty + r) * K + k0 + tx] = f2bf(t[tx][ty + r]);
}

// ---------- K2: fused transpose + spectral filter ----------
// Per block (b, d-tile of 128): load x[b][:, d0:d0+128] fp32 directly,
// transpose+bf16 into Bs[d][t] via 4 quarter-passes (12.4KB fp32 staging),
// then xl = Fl @ x[b], xh = Fh @ x[b] via MFMA. Kills xt_k + the xT buffer.
__global__ void __launch_bounds__(256) filter_fused_k(
    const float* __restrict__ x, const u16* __restrict__ FlB,
    const u16* __restrict__ FhB, u16* __restrict__ xl, u16* __restrict__ xh) {
  __shared__ __align__(16) u16 Bs[128 * SEQ];        // [128 d][96 t], 24.0 KB
  __shared__ __align__(16) u16 As0[2 * SEQ * SEQ];   // [2][96 s][96 t], 36.0 KB
  __shared__ float xs[SEQ * 33];                     // quarter-stage [96 t][32 d]+pad, 12.4 KB
  int tid = threadIdx.x;
  int lane = tid & 63, w = tid >> 6;
  int b = blockIdx.x, d0 = blockIdx.y * 128;

  // stage A (Fl then Fh) async: 2 x 1152 16B-chunks (overlaps the transpose)
  #pragma unroll
  for (int it = 0; it < 9; it++) {
    int c = it * 256 + tid;      // 0..2303
    const u16* src = (c < 1152) ? (FlB + c * 8) : (FhB + (c - 1152) * 8);
    g2l16(src, (char*)As0 + ((it * 256 + w * 64) << 4));
  }

  // build Bs[d][t] from x in 4 quarter-passes of 32 d-columns
  const float* xb = x + (size_t)b * SEQ * DM + d0;
  u32* BsW = (u32*)Bs;
  #pragma unroll
  for (int q = 0; q < 4; q++) {
    // load [96 t][32 d] fp32, coalesced float4
    #pragma unroll
    for (int v = 0; v < 3; v++) {
      int c = v * 256 + tid;         // 0..767
      int t = c >> 3, f = (c & 7) << 2;
      float4 fv = *(const float4*)(xb + (size_t)t * DM + q * 32 + f);
      xs[t * 33 + f + 0] = fv.x;
      xs[t * 33 + f + 1] = fv.y;
      xs[t * 33 + f + 2] = fv.z;
      xs[t * 33 + f + 3] = fv.w;
    }
    __syncthreads();
    // pack columns: Bs[q*32+dl][t], 2 t-values per u32 word
    #pragma unroll
    for (int v = 0; v < 6; v++) {
      int c = v * 256 + tid;         // 0..1535
      int dl = c / 48, tw = c % 48;
      u32 lo = (u32)f2bf(xs[(2 * tw) * 33 + dl]);
      u32 hi = (u32)f2bf(xs[(2 * tw + 1) * 33 + dl]);
      BsW[(size_t)(q * 32 + dl) * 48 + tw] = lo | (hi << 16);
    }
    __syncthreads();  // also drains As g2l16 on the last pass
  }

  const int l15 = lane & 15, lq = lane >> 4;
  f32x4 acc[2][6][2] = {};
  #pragma unroll
  for (int ks = 0; ks < 3; ks++) {
    int kt = ks * 32;
    bf16x8 bfr[2];
    #pragma unroll
    for (int j = 0; j < 2; j++)
      bfr[j] = *(const bf16x8*)&Bs[(w * 32 + j * 16 + l15) * SEQ + kt + lq * 8];
    #pragma unroll
    for (int f = 0; f < 2; f++)
      #pragma unroll
      for (int i = 0; i < 6; i++) {
        bf16x8 afr = *(const bf16x8*)&As0[f * SEQ * SEQ + (i * 16 + l15) * SEQ + kt + lq * 8];
        #pragma unroll
        for (int j = 0; j < 2; j++)
          acc[f][i][j] = __builtin_amdgcn_mfma_f32_16x16x32_bf16(afr, bfr[j], acc[f][i][j], 0, 0, 0);
      }
  }
  #pragma unroll
  for (int f = 0; f < 2; f++) {
    u16* dst = f ? xh : xl;
    #pragma unroll
    for (int i = 0; i < 6; i++)
      #pragma unroll
      for (int j = 0; j < 2; j++) {
        int d = d0 + w * 32 + j * 16 + l15;
        #pragma unroll
        for (int r = 0; r < 4; r++) {
          int s = i * 16 + lq * 4 + r;
          dst[((size_t)b * SEQ + s) * DM + d] = f2bf(acc[f][i][j][r]);
        }
      }
  }
}

// ---------- K3: proj GEMM, double-buffered LDS, 1 barrier/K-step ----------
// C[M,512] = A[M,512]bf16 @ Wt[512,512]^T + bias. 128x128 tile, 4 waves.
__global__ void __launch_bounds__(256) gemm_proj_mfma_k(
    const u16* __restrict__ xl, const u16* __restrict__ xh,
    const u16* __restrict__ Wlt, const u16* __restrict__ Wht,
    const float* __restrict__ bl, const float* __restrict__ bh,
    u16* __restrict__ yl, u16* __restrict__ yh) {
  const u16* A = blockIdx.z ? xh : xl;
  const u16* Bt = blockIdx.z ? Wht : Wlt;
  const float* bias = blockIdx.z ? bh : bl;
  u16* C = blockIdx.z ? yh : yl;

  // per buffer: A[128][32] (8KB) then B[128][32] (8KB)
  __shared__ __align__(16) char stg[2][16384];
  const int m0 = blockIdx.x * 128;
  const int n0 = blockIdx.y * 128;
  const int tid = threadIdx.x;
  const int lane = tid & 63;
  const int w = tid >> 6;
  const int wm = w & 1, wn = w >> 1;  // 2x2 waves, each 64x64
  const int l15 = lane & 15;
  const int lq = lane >> 4;  // 0..3

  f32x4 acc[4][4] = {};

  // stage K-step ks into buffer b (1024 chunks of 16B: 512 A + 512 B)
  auto stage = [&](int b, int ks) {
    const int kt = ks * 32;
    #pragma unroll
    for (int it = 0; it < 4; it++) {
      int c = it * 256 + tid;
      int row = (c & 511) >> 2, ce = (c & 3) << 3;
      const u16* src = (c < 512)
          ? A  + (size_t)(m0 + row) * 512 + kt + ce
          : Bt + (size_t)(n0 + row) * 512 + kt + ce;
      g2l16(src, stg[b] + ((it * 256 + w * 64) << 4));
    }
  };

  stage(0, 0);
  __syncthreads();

  #pragma unroll 2
  for (int ks = 0; ks < 16; ks++) {
    const int cur = ks & 1;
    if (ks < 15) stage(cur ^ 1, ks + 1);   // loads fly while we compute
    const u16* As = (const u16*)stg[cur];
    const u16* Bs = As + 4096;  // 8KB offset
    bf16x8 af[4], bf[4];
    #pragma unroll
    for (int i = 0; i < 4; i++)
      af[i] = *(const bf16x8*)&As[(wm * 64 + i * 16 + l15) * 32 + lq * 8];
    #pragma unroll
    for (int j = 0; j < 4; j++)
      bf[j] = *(const bf16x8*)&Bs[(wn * 64 + j * 16 + l15) * 32 + lq * 8];
    #pragma unroll
    for (int i = 0; i < 4; i++)
      #pragma unroll
      for (int j = 0; j < 4; j++)
        acc[i][j] = __builtin_amdgcn_mfma_f32_16x16x32_bf16(af[i], bf[j], acc[i][j], 0, 0, 0);
    __syncthreads();  // drains vmcnt (next buf ready) + read-done on cur
  }

  #pragma unroll
  for (int j = 0; j < 4; j++) {
    int n = n0 + wn * 64 + j * 16 + l15;
    float bv = bias[n];
    #pragma unroll
    for (int i = 0; i < 4; i++) {
      int mrow = m0 + wm * 64 + i * 16 + lq * 4;
      #pragma unroll
      for (int r = 0; r < 4; r++)
        C[(size_t)(mrow + r) * 512 + n] = f2bf(acc[i][j][r] + bv);
    }
  }
}

// ---------- K4: gate GEMM (K=1024 over concat(yl,yh)), sigmoid -> g bf16 ----------
// Round-0 epilogue (low VGPR) + 1-barrier double-buffer loop.
__global__ void __launch_bounds__(256) gemm_gate_mfma_k(
    const u16* __restrict__ yl, const u16* __restrict__ yh,
    const u16* __restrict__ Wgt, const float* __restrict__ bg,
    u16* __restrict__ g) {
  __shared__ __align__(16) char stg[2][16384];
  const int m0 = blockIdx.x * 128;
  const int n0 = blockIdx.y * 128;
  const int tid = threadIdx.x;
  const int lane = tid & 63;
  const int w = tid >> 6;
  const int wm = w & 1, wn = w >> 1;
  const int l15 = lane & 15;
  const int lq = lane >> 4;

  // stage K-step ks into buffer b (1024 chunks: 512 A + 512 B)
  auto stage = [&](int b, int ks) {
    const int kt = ks * 32;
    const int ka = kt & 511;
    const u16* Ak = (ks < 16) ? yl : yh;   // concat A along K
    #pragma unroll
    for (int it = 0; it < 4; it++) {
      int c = it * 256 + tid;
      int row = (c & 511) >> 2, ce = (c & 3) << 3;
      const u16* src = (c < 512)
          ? Ak  + (size_t)(m0 + row) * 512 + ka + ce
          : Wgt + (size_t)(n0 + row) * 1024 + kt + ce;
      g2l16(src, stg[b] + ((it * 256 + w * 64) << 4));
    }
  };

  f32x4 acc[4][4] = {};

  stage(0, 0);
  __syncthreads();

  #pragma unroll 2
  for (int ks = 0; ks < 32; ks++) {
    const int cur = ks & 1;
    if (ks < 31) stage(cur ^ 1, ks + 1);
    const u16* As = (const u16*)stg[cur];
    const u16* Bs = As + 4096;  // 8KB offset
    bf16x8 af[4], bf[4];
    #pragma unroll
    for (int i = 0; i < 4; i++)
      af[i] = *(const bf16x8*)&As[(wm * 64 + i * 16 + l15) * 32 + lq * 8];
    #pragma unroll
    for (int j = 0; j < 4; j++)
      bf[j] = *(const bf16x8*)&Bs[(wn * 64 + j * 16 + l15) * 32 + lq * 8];
    #pragma unroll
    for (int i = 0; i < 4; i++)
      #pragma unroll
      for (int j = 0; j < 4; j++)
        acc[i][j] = __builtin_amdgcn_mfma_f32_16x16x32_bf16(af[i], bf[j], acc[i][j], 0, 0, 0);
    __syncthreads();
  }

  #pragma unroll
  for (int j = 0; j < 4; j++) {
    int n = n0 + wn * 64 + j * 16 + l15;
    float bv = bg[n];
    #pragma unroll
    for (int i = 0; i < 4; i++) {
      int mrow = m0 + wm * 64 + i * 16 + lq * 4;
      #pragma unroll
      for (int r = 0; r < 4; r++) {
        float z = acc[i][j][r] + bv;
        g[(size_t)(mrow + r) * 512 + n] = f2bf(1.0f / (1.0f + __expf(-z)));
      }
    }
  }
}

// ---------- K5: y = x + g*yl + (1-g)*yh ; LayerNorm(y)*gamma + beta ----------
__global__ void __launch_bounds__(256) final_ln_k(
    const float* __restrict__ x, const u16* __restrict__ yl,
    const u16* __restrict__ yh, const u16* __restrict__ g,
    const float* __restrict__ gamma, const float* __restrict__ beta,
    float* __restrict__ out) {
  __shared__ float red[8];
  int r = blockIdx.x;
  size_t base = (size_t)r * 512;
  float vv[2];
  float sum = 0.f, sumsq = 0.f;
  #pragma unroll
  for (int j = 0; j < 2; j++) {
    int e = threadIdx.x + j * 256;
    float lv = bf2f(yl[base + e]);
    float hv = bf2f(yh[base + e]);
    float gv = bf2f(g[base + e]);
    float v = x[base + e] + gv * lv + (1.f - gv) * hv;
    vv[j] = v;
    sum += v;
    sumsq += v * v;
  }
  #pragma unroll
  for (int off = 32; off; off >>= 1) {
    sum += __shfl_down(sum, off);
    sumsq += __shfl_down(sumsq, off);
  }
  int wid = threadIdx.x >> 6;
  if ((threadIdx.x & 63) == 0) {
    red[wid] = sum;
    red[4 + wid] = sumsq;
  }
  __syncthreads();
  sum = red[0] + red[1] + red[2] + red[3];
  sumsq = red[4] + red[5] + red[6] + red[7];
  float mu = sum * (1.f / 512.f);
  float var = sumsq * (1.f / 512.f) - mu * mu;
  float inv = rsqrtf(var + 1e-5f);
  #pragma unroll
  for (int j = 0; j < 2; j++) {
    int e = threadIdx.x + j * 256;
    out[base + e] = (vv[j] - mu) * inv * gamma[e] + beta[e];
  }
}

extern "C" void kernel_launch(void* const* d_in, const int* in_sizes, int n_in,
                              void* d_out, int out_size, void* d_ws, size_t ws_size,
                              hipStream_t stream) {
  const float* x     = (const float*)d_in[0];
  const float* fw    = (const float*)d_in[1];
  const float* Wl    = (const float*)d_in[2];
  const float* bl    = (const float*)d_in[3];
  const float* Wh    = (const float*)d_in[4];
  const float* bh    = (const float*)d_in[5];
  const float* Wg    = (const float*)d_in[6];
  const float* bg    = (const float*)d_in[7];
  const float* gamma = (const float*)d_in[8];
  const float* beta  = (const float*)d_in[9];
  float* out = (float*)d_out;

  char* ws = (char*)d_ws;
  u16* FlB = (u16*)ws;                      // 96*96 bf16
  u16* FhB = FlB + SEQ * SEQ;
  u16* Wlt = (u16*)(ws + 64 * 1024);        // 512x512 bf16 [N][K]
  u16* Wht = Wlt + 512 * 512;
  u16* Wgt = Wht + 512 * 512;               // 512x1024 [N][K]
  size_t tsz = (size_t)MROWS * 512;         // 25165824 elems
  u16* xl = (u16*)(ws + 4 * 1024 * 1024);
  u16* xh = xl + tsz;
  u16* yl = xh + tsz;
  u16* yh = yl + tsz;
  u16* gbuf = xl;  // xl dead after proj GEMM -> reuse for gate output

  build_filters_k<<<dim3(36), dim3(256), 0, stream>>>(fw, FlB, FhB);
  transpose_w_k<<<dim3(16, 16), dim3(256), 0, stream>>>(Wl, Wlt, 512, 512);
  transpose_w_k<<<dim3(16, 16), dim3(256), 0, stream>>>(Wh, Wht, 512, 512);
  transpose_w_k<<<dim3(32, 16), dim3(256), 0, stream>>>(Wg, Wgt, 1024, 512);
  filter_fused_k<<<dim3(NBATCH, DM / 128), dim3(256), 0, stream>>>(x, FlB, FhB, xl, xh);
  gemm_proj_mfma_k<<<dim3(MROWS / 128, 4, 2), dim3(256), 0, stream>>>(
      xl, xh, Wlt, Wht, bl, bh, yl, yh);
  gemm_gate_mfma_k<<<dim3(MROWS / 128, 4), dim3(256), 0, stream>>>(yl, yh, Wgt, bg, gbuf);
  final_ln_k<<<dim3(MROWS), dim3(256), 0, stream>>>(x, yl, yh, gbuf, gamma, beta, out);
}